// Round 8
// baseline (291.016 us; speedup 1.0000x reference)
//
#include <hip/hip_runtime.h>
#include <hip/hip_bf16.h>

#define NN 4096
#define DD 1024
#define HH 16
#define HDD 64
#define NO 24
#define QKV_N (3 * DD)

typedef short bf16x8 __attribute__((ext_vector_type(8)));
typedef float f32x4 __attribute__((ext_vector_type(4)));
typedef unsigned short ushort;

// fp32 -> bf16 (RNE)
__device__ __forceinline__ ushort f2bf(float f) {
    unsigned u = __float_as_uint(f);
    return (ushort)((u + 0x7FFFu + ((u >> 16) & 1u)) >> 16);
}
__device__ __forceinline__ float bf2f(ushort u) {
    return __uint_as_float(((unsigned)u) << 16);
}

__device__ __forceinline__ void gload16(const void* g, void* l) {
    __builtin_amdgcn_global_load_lds((const __attribute__((address_space(1))) void*)g,
                                     (__attribute__((address_space(3))) void*)l, 16, 0, 0);
}

// ---------------------------------------------------------------------------
// elementwise fp32 -> bf16
// ---------------------------------------------------------------------------
__global__ __launch_bounds__(256) void f2b_kernel(const float* __restrict__ in,
                                                  ushort* __restrict__ out, int n4) {
    int i = blockIdx.x * 256 + threadIdx.x;
    if (i < n4) {
        float4 v = ((const float4*)in)[i];
        ushort4 o;
        o.x = f2bf(v.x); o.y = f2bf(v.y); o.z = f2bf(v.z); o.w = f2bf(v.w);
        ((ushort4*)out)[i] = o;
    }
}

// ---------------------------------------------------------------------------
// transpose fp32 [R,C] -> bf16 [C,R]
// ---------------------------------------------------------------------------
__global__ __launch_bounds__(256) void transpose_f2b(const float* __restrict__ in,
                                                     ushort* __restrict__ out,
                                                     int R, int C) {
    __shared__ float tile[32][33];
    const int c0 = blockIdx.x * 32, r0 = blockIdx.y * 32;
    const int tx = threadIdx.x & 31, ty = threadIdx.x >> 5;
#pragma unroll
    for (int i = 0; i < 32; i += 8)
        tile[ty + i][tx] = in[(size_t)(r0 + ty + i) * C + c0 + tx];
    __syncthreads();
#pragma unroll
    for (int i = 0; i < 32; i += 8)
        out[(size_t)(c0 + ty + i) * R + r0 + tx] = f2bf(tile[tx][ty + i]);
}

// ---------------------------------------------------------------------------
// bf16 MFMA GEMM: C = A[M,K] @ BT[N,K]^T + bias
// 128x128 tile, BK=32, 4 waves x (4x4) 16x16x32 frags, global_load_lds dbuf,
// XOR-swizzled LDS (slot ^= (row>>1)&3) via pre-swizzled global source.
// OP==0: fp32 out[m*N+n] = acc + bias
// OP==2: bf16 out = multT[n*M+m] * sigmoid(acc + bias)   (multT bf16 [N][M])
// OP==3: fp32 outT[n*M+m] = acc + bias  (transposed, float4 along m)
// ---------------------------------------------------------------------------
template <int OP>
__global__ __launch_bounds__(256) void mfma_gemm(const ushort* __restrict__ A,
                                                 const ushort* __restrict__ BT,
                                                 const float* __restrict__ bias,
                                                 const void* __restrict__ mult,
                                                 void* __restrict__ Cout,
                                                 int M, int N, int K) {
    __shared__ ushort sA[2][128 * 32];
    __shared__ ushort sB[2][128 * 32];

    const int tid = threadIdx.x;
    const int lane = tid & 63;
    const int w = tid >> 6;
    const int wr = w >> 1, wc = w & 1;
    const int m0 = blockIdx.y * 128, n0 = blockIdx.x * 128;

    const int row0 = tid >> 2, slot = tid & 3;
    const int row1 = row0 + 64;
    const int sw0 = slot ^ ((row0 >> 1) & 3);
    const int sw1 = slot ^ ((row1 >> 1) & 3);
    const int dst0 = (tid & ~63) * 8;
    const int dst1 = (256 + (tid & ~63)) * 8;

    const size_t aOff0 = (size_t)(m0 + row0) * K + sw0 * 8;
    const size_t aOff1 = (size_t)(m0 + row1) * K + sw1 * 8;
    const size_t bOff0 = (size_t)(n0 + row0) * K + sw0 * 8;
    const size_t bOff1 = (size_t)(n0 + row1) * K + sw1 * 8;

    const int ks = lane >> 4;
    int aRd[4], bRd[4];
#pragma unroll
    for (int m = 0; m < 4; ++m) {
        int r = wr * 64 + m * 16 + (lane & 15);
        aRd[m] = r * 64 + ((ks ^ ((r >> 1) & 3)) << 4);
    }
#pragma unroll
    for (int n = 0; n < 4; ++n) {
        int r = wc * 64 + n * 16 + (lane & 15);
        bRd[n] = r * 64 + ((ks ^ ((r >> 1) & 3)) << 4);
    }

    f32x4 acc[4][4];
#pragma unroll
    for (int m = 0; m < 4; ++m)
#pragma unroll
        for (int n = 0; n < 4; ++n) acc[m][n] = (f32x4){0.f, 0.f, 0.f, 0.f};

#define STAGE(buf, k0)                                              \
    do {                                                            \
        gload16(A + aOff0 + (k0), &sA[buf][dst0]);                  \
        gload16(A + aOff1 + (k0), &sA[buf][dst1]);                  \
        gload16(BT + bOff0 + (k0), &sB[buf][dst0]);                 \
        gload16(BT + bOff1 + (k0), &sB[buf][dst1]);                 \
    } while (0)

    const int NS = K >> 5;
    STAGE(0, 0);
    for (int s = 0; s < NS; ++s) {
        const int cur = s & 1;
        __syncthreads();
        if (s + 1 < NS) STAGE(cur ^ 1, (s + 1) * 32);
        const char* pa = (const char*)sA[cur];
        const char* pb = (const char*)sB[cur];
        bf16x8 af[4], bfr[4];
#pragma unroll
        for (int m = 0; m < 4; ++m) af[m] = *(const bf16x8*)(pa + aRd[m]);
#pragma unroll
        for (int n = 0; n < 4; ++n) bfr[n] = *(const bf16x8*)(pb + bRd[n]);
#pragma unroll
        for (int m = 0; m < 4; ++m)
#pragma unroll
            for (int n = 0; n < 4; ++n)
                acc[m][n] = __builtin_amdgcn_mfma_f32_16x16x32_bf16(af[m], bfr[n],
                                                                    acc[m][n], 0, 0, 0);
    }
#undef STAGE

    // C/D layout: col = lane&15, row = (lane>>4)*4 + j
    const int fr = lane & 15, fq = lane >> 4;
#pragma unroll
    for (int m = 0; m < 4; ++m) {
        const int rbase = m0 + wr * 64 + m * 16 + fq * 4;
#pragma unroll
        for (int n = 0; n < 4; ++n) {
            const int col = n0 + wc * 64 + n * 16 + fr;
            const float bv = bias[col];
            if (OP == 3) {
                float4 o4;
                o4.x = acc[m][n][0] + bv; o4.y = acc[m][n][1] + bv;
                o4.z = acc[m][n][2] + bv; o4.w = acc[m][n][3] + bv;
                *(float4*)&((float*)Cout)[(size_t)col * M + rbase] = o4;
            } else if (OP == 2) {
                const ushort4 mu =
                    *(const ushort4*)&((const ushort*)mult)[(size_t)col * M + rbase];
                const float mv[4] = {bf2f(mu.x), bf2f(mu.y), bf2f(mu.z), bf2f(mu.w)};
#pragma unroll
                for (int j = 0; j < 4; ++j) {
                    float v = acc[m][n][j] + bv;
                    v = mv[j] / (1.f + expf(-v));
                    ((ushort*)Cout)[(size_t)(rbase + j) * N + col] = f2bf(v);
                }
            } else {
#pragma unroll
                for (int j = 0; j < 4; ++j) {
                    ((float*)Cout)[(size_t)(rbase + j) * N + col] = acc[m][n][j] + bv;
                }
            }
        }
    }
}

// ---------------------------------------------------------------------------
// Attention v2: one BLOCK (4 waves) per (h, 64-t block); lane = t.
// Waves split the d-loop 4 ways (16 d each) for both QK and PV, giving
// 4096 waves (4/SIMD) to hide load latency (v1 had 1 wave/SIMD, 12% VALU).
// Partial scores reduced via conflict-free psum[w][j][lane] LDS; softmax
// finished redundantly per wave (lane-local, no shuffles).
// Invalid taps: clamped gather + cndmask (score->pos_bias stays in denom,
// prob->0 kills value term) — matches reference zero-padded gather.
// ---------------------------------------------------------------------------
__global__ __launch_bounds__(256) void attn_kernel(const float* __restrict__ qkvT,
                                                   const float* __restrict__ pos_bias,
                                                   ushort* __restrict__ outT) {
    constexpr int OFF[NO] = {0, 1, 2, 3, 4, 6, 8, 12, 16, 24, 32, 48, 64, 96, 128,
                             192, 256, 384, 512, 768, 1024, 1536, 2048, 3072};
    __shared__ float psum[4][NO][64];

    // bijective XCD swizzle over 1024 blocks: 8 chunks of 128 (~2 heads/XCD)
    const int bid = (blockIdx.x & 7) * 128 + (blockIdx.x >> 3);
    const int w = threadIdx.x >> 6;      // wave 0..3 -> d quarter
    const int lane = threadIdx.x & 63;
    const int h = bid >> 6;
    const int t = (bid & 63) * 64 + lane;

    const float* qd = qkvT + (size_t)(h * HDD) * NN;  // + d*NN
    const float* kd = qd + (size_t)DD * NN;
    const float* vd = qd + (size_t)(2 * DD) * NN;

    int kidx[NO];
#pragma unroll
    for (int j = 0; j < NO; ++j) kidx[j] = max(t - OFF[j], 0);

    // ---- QK partial over d in [16w, 16w+16) ----
    float sc[NO];
#pragma unroll
    for (int j = 0; j < NO; ++j) sc[j] = 0.f;

    const float* qw = qd + (size_t)(w * 16) * NN;
    const float* kw = kd + (size_t)(w * 16) * NN;
#pragma unroll 2
    for (int dd = 0; dd < 16; ++dd) {
        const float qv = qw[(size_t)dd * NN + t];
        const float* kr = kw + (size_t)dd * NN;
#pragma unroll
        for (int j = 0; j < NO; ++j) sc[j] = fmaf(qv, kr[kidx[j]], sc[j]);
    }
#pragma unroll
    for (int j = 0; j < NO; ++j) psum[w][j][lane] = sc[j];
    __syncthreads();
#pragma unroll
    for (int j = 0; j < NO; ++j)
        sc[j] = (psum[0][j][lane] + psum[1][j][lane]) +
                (psum[2][j][lane] + psum[3][j][lane]);

    // ---- softmax over 24 taps (redundant per wave, lane-local) ----
#pragma unroll
    for (int j = 0; j < NO; ++j) {
        const float pb = pos_bias[j * HH + h];
        sc[j] = (t >= OFF[j]) ? fmaf(sc[j], 0.125f, pb) : pb;
    }
    float mx = sc[0];
#pragma unroll
    for (int j = 1; j < NO; ++j) mx = fmaxf(mx, sc[j]);
    float den = 0.f;
#pragma unroll
    for (int j = 0; j < NO; ++j) {
        sc[j] = __expf(sc[j] - mx);
        den += sc[j];
    }
    const float inv = 1.f / den;
#pragma unroll
    for (int j = 0; j < NO; ++j) sc[j] = (t >= OFF[j]) ? sc[j] * inv : 0.f;

    // ---- PV: this wave produces d in [16w, 16w+16) ----
    const float* vw = vd + (size_t)(w * 16) * NN;
    ushort* ow = outT + (size_t)(h * HDD + w * 16) * NN;
#pragma unroll 2
    for (int dd = 0; dd < 16; ++dd) {
        const float* vr = vw + (size_t)dd * NN;
        float o = 0.f;
#pragma unroll
        for (int j = 0; j < NO; ++j) o = fmaf(sc[j], vr[kidx[j]], o);
        ow[(size_t)dd * NN + t] = f2bf(o);
    }
}

extern "C" void kernel_launch(void* const* d_in, const int* in_sizes, int n_in,
                              void* d_out, int out_size, void* d_ws, size_t ws_size,
                              hipStream_t stream) {
    const float* x = (const float*)d_in[0];
    const float* Wqkv = (const float*)d_in[1];
    const float* bqkv = (const float*)d_in[2];
    const float* Wout = (const float*)d_in[3];
    const float* bout = (const float*)d_in[4];
    const float* Wgate = (const float*)d_in[5];
    const float* bgate = (const float*)d_in[6];
    const float* pos_bias = (const float*)d_in[7];
    float* out = (float*)d_out;

    // workspace layout (74 MB peak)
    char* ws = (char*)d_ws;
    ushort* xb = (ushort*)ws;                            // 8 MB  [4096,1024] bf16
    ushort* WqkvT = (ushort*)(ws + ((size_t)8 << 20));   // 6 MB  [3072,1024] bf16
    ushort* WgateT = (ushort*)(ws + ((size_t)14 << 20)); // 2 MB
    ushort* WoutT = (ushort*)(ws + ((size_t)16 << 20));  // 2 MB
    float* qkvT = (float*)(ws + ((size_t)18 << 20));     // 48 MB [3072][4096] fp32
    ushort* outT = (ushort*)(ws + ((size_t)66 << 20));   // 8 MB  [1024][4096] bf16
    ushort* gated = (ushort*)(ws + ((size_t)18 << 20));  // overlays qkvT (dead)

    // 0) converts / transposes
    f2b_kernel<<<(NN * DD / 4 + 255) / 256, 256, 0, stream>>>(x, xb, NN * DD / 4);
    transpose_f2b<<<dim3(QKV_N / 32, DD / 32), 256, 0, stream>>>(Wqkv, WqkvT, DD, QKV_N);
    transpose_f2b<<<dim3(DD / 32, DD / 32), 256, 0, stream>>>(Wgate, WgateT, DD, DD);
    transpose_f2b<<<dim3(DD / 32, DD / 32), 256, 0, stream>>>(Wout, WoutT, DD, DD);

    // 1) qkvT = (x @ Wqkv + bqkv)^T  fp32 [3072][4096]
    mfma_gemm<3><<<dim3(QKV_N / 128, NN / 128), 256, 0, stream>>>(
        xb, WqkvT, bqkv, nullptr, qkvT, NN, QKV_N, DD);
    // 2) attention -> outT bf16 [1024][4096]  (1024 blocks, 4 waves each)
    attn_kernel<<<NN / 64 * HH, 256, 0, stream>>>(qkvT, pos_bias, outT);
    // 3) gated = outT^T * sigmoid(x @ Wgate + bgate)  bf16 [4096][1024]
    mfma_gemm<2><<<dim3(DD / 128, NN / 128), 256, 0, stream>>>(
        xb, WgateT, bgate, outT, gated, NN, DD, DD);
    // 4) out = gated @ Wout + bout  fp32
    mfma_gemm<0><<<dim3(DD / 128, NN / 128), 256, 0, stream>>>(
        gated, WoutT, bout, nullptr, out, NN, DD, DD);
}

// Round 9
// 268.770 us; speedup vs baseline: 1.0828x; 1.0828x over previous
//
#include <hip/hip_runtime.h>
#include <hip/hip_bf16.h>

#define NN 4096
#define DD 1024
#define HH 16
#define HDD 64
#define NO 24
#define QKV_N (3 * DD)

typedef short bf16x8 __attribute__((ext_vector_type(8)));
typedef float f32x4 __attribute__((ext_vector_type(4)));
typedef unsigned short ushort;

// fp32 -> bf16 (RNE)
__device__ __forceinline__ ushort f2bf(float f) {
    unsigned u = __float_as_uint(f);
    return (ushort)((u + 0x7FFFu + ((u >> 16) & 1u)) >> 16);
}
__device__ __forceinline__ float bf2f(ushort u) {
    return __uint_as_float(((unsigned)u) << 16);
}

__device__ __forceinline__ void gload16(const void* g, void* l) {
    __builtin_amdgcn_global_load_lds((const __attribute__((address_space(1))) void*)g,
                                     (__attribute__((address_space(3))) void*)l, 16, 0, 0);
}

// ---------------------------------------------------------------------------
// elementwise fp32 -> bf16
// ---------------------------------------------------------------------------
__global__ __launch_bounds__(256) void f2b_kernel(const float* __restrict__ in,
                                                  ushort* __restrict__ out, int n4) {
    int i = blockIdx.x * 256 + threadIdx.x;
    if (i < n4) {
        float4 v = ((const float4*)in)[i];
        ushort4 o;
        o.x = f2bf(v.x); o.y = f2bf(v.y); o.z = f2bf(v.z); o.w = f2bf(v.w);
        ((ushort4*)out)[i] = o;
    }
}

// ---------------------------------------------------------------------------
// transpose fp32 [R,C] -> bf16 [C,R]
// ---------------------------------------------------------------------------
__global__ __launch_bounds__(256) void transpose_f2b(const float* __restrict__ in,
                                                     ushort* __restrict__ out,
                                                     int R, int C) {
    __shared__ float tile[32][33];
    const int c0 = blockIdx.x * 32, r0 = blockIdx.y * 32;
    const int tx = threadIdx.x & 31, ty = threadIdx.x >> 5;
#pragma unroll
    for (int i = 0; i < 32; i += 8)
        tile[ty + i][tx] = in[(size_t)(r0 + ty + i) * C + c0 + tx];
    __syncthreads();
#pragma unroll
    for (int i = 0; i < 32; i += 8)
        out[(size_t)(c0 + ty + i) * R + r0 + tx] = f2bf(tile[tx][ty + i]);
}

// ---------------------------------------------------------------------------
// bf16 MFMA GEMM: C = A[M,K] @ BT[N,K]^T + bias
// 128x128 tile, BK=32, 4 waves x (4x4) 16x16x32 frags, global_load_lds dbuf,
// XOR-swizzled LDS (slot ^= (row>>1)&3) via pre-swizzled global source.
// OP==0: fp32 out[m*N+n] = acc + bias
// OP==2: bf16 out = multT[n*M+m] * sigmoid(acc + bias)   (multT bf16 [N][M])
// OP==3: bf16 outT[n*M+m] = acc + bias  (transposed, ushort4 along m)
// ---------------------------------------------------------------------------
template <int OP>
__global__ __launch_bounds__(256) void mfma_gemm(const ushort* __restrict__ A,
                                                 const ushort* __restrict__ BT,
                                                 const float* __restrict__ bias,
                                                 const void* __restrict__ mult,
                                                 void* __restrict__ Cout,
                                                 int M, int N, int K) {
    __shared__ ushort sA[2][128 * 32];
    __shared__ ushort sB[2][128 * 32];

    const int tid = threadIdx.x;
    const int lane = tid & 63;
    const int w = tid >> 6;
    const int wr = w >> 1, wc = w & 1;
    const int m0 = blockIdx.y * 128, n0 = blockIdx.x * 128;

    const int row0 = tid >> 2, slot = tid & 3;
    const int row1 = row0 + 64;
    const int sw0 = slot ^ ((row0 >> 1) & 3);
    const int sw1 = slot ^ ((row1 >> 1) & 3);
    const int dst0 = (tid & ~63) * 8;
    const int dst1 = (256 + (tid & ~63)) * 8;

    const size_t aOff0 = (size_t)(m0 + row0) * K + sw0 * 8;
    const size_t aOff1 = (size_t)(m0 + row1) * K + sw1 * 8;
    const size_t bOff0 = (size_t)(n0 + row0) * K + sw0 * 8;
    const size_t bOff1 = (size_t)(n0 + row1) * K + sw1 * 8;

    const int ks = lane >> 4;
    int aRd[4], bRd[4];
#pragma unroll
    for (int m = 0; m < 4; ++m) {
        int r = wr * 64 + m * 16 + (lane & 15);
        aRd[m] = r * 64 + ((ks ^ ((r >> 1) & 3)) << 4);
    }
#pragma unroll
    for (int n = 0; n < 4; ++n) {
        int r = wc * 64 + n * 16 + (lane & 15);
        bRd[n] = r * 64 + ((ks ^ ((r >> 1) & 3)) << 4);
    }

    f32x4 acc[4][4];
#pragma unroll
    for (int m = 0; m < 4; ++m)
#pragma unroll
        for (int n = 0; n < 4; ++n) acc[m][n] = (f32x4){0.f, 0.f, 0.f, 0.f};

#define STAGE(buf, k0)                                              \
    do {                                                            \
        gload16(A + aOff0 + (k0), &sA[buf][dst0]);                  \
        gload16(A + aOff1 + (k0), &sA[buf][dst1]);                  \
        gload16(BT + bOff0 + (k0), &sB[buf][dst0]);                 \
        gload16(BT + bOff1 + (k0), &sB[buf][dst1]);                 \
    } while (0)

    const int NS = K >> 5;
    STAGE(0, 0);
    for (int s = 0; s < NS; ++s) {
        const int cur = s & 1;
        __syncthreads();
        if (s + 1 < NS) STAGE(cur ^ 1, (s + 1) * 32);
        const char* pa = (const char*)sA[cur];
        const char* pb = (const char*)sB[cur];
        bf16x8 af[4], bfr[4];
#pragma unroll
        for (int m = 0; m < 4; ++m) af[m] = *(const bf16x8*)(pa + aRd[m]);
#pragma unroll
        for (int n = 0; n < 4; ++n) bfr[n] = *(const bf16x8*)(pb + bRd[n]);
#pragma unroll
        for (int m = 0; m < 4; ++m)
#pragma unroll
            for (int n = 0; n < 4; ++n)
                acc[m][n] = __builtin_amdgcn_mfma_f32_16x16x32_bf16(af[m], bfr[n],
                                                                    acc[m][n], 0, 0, 0);
    }
#undef STAGE

    // C/D layout: col = lane&15, row = (lane>>4)*4 + j
    const int fr = lane & 15, fq = lane >> 4;
#pragma unroll
    for (int m = 0; m < 4; ++m) {
        const int rbase = m0 + wr * 64 + m * 16 + fq * 4;
#pragma unroll
        for (int n = 0; n < 4; ++n) {
            const int col = n0 + wc * 64 + n * 16 + fr;
            const float bv = bias[col];
            if (OP == 3) {
                ushort4 o4;
                o4.x = f2bf(acc[m][n][0] + bv);
                o4.y = f2bf(acc[m][n][1] + bv);
                o4.z = f2bf(acc[m][n][2] + bv);
                o4.w = f2bf(acc[m][n][3] + bv);
                *(ushort4*)&((ushort*)Cout)[(size_t)col * M + rbase] = o4;
            } else if (OP == 2) {
                const ushort4 mu =
                    *(const ushort4*)&((const ushort*)mult)[(size_t)col * M + rbase];
                const float mv[4] = {bf2f(mu.x), bf2f(mu.y), bf2f(mu.z), bf2f(mu.w)};
#pragma unroll
                for (int j = 0; j < 4; ++j) {
                    float v = acc[m][n][j] + bv;
                    v = mv[j] / (1.f + expf(-v));
                    ((ushort*)Cout)[(size_t)(rbase + j) * N + col] = f2bf(v);
                }
            } else {
#pragma unroll
                for (int j = 0; j < 4; ++j) {
                    ((float*)Cout)[(size_t)(rbase + j) * N + col] = acc[m][n][j] + bv;
                }
            }
        }
    }
}

// ---------------------------------------------------------------------------
// Attention v3 = v1 structure + bf16 qkvT. One wave per (h, 64-t block),
// lane = t. Scores lane-local; d-loop has only coalesced 2B loads + FMAs.
// bf16 halves gather bytes (840->420 MB), halves cache lines per load
// (2 vs 4), and makes the 2-heads/XCD working set (3 MB) L2-resident.
// Invalid taps: clamped gather + cndmask (score->pos_bias in denom, p->0).
// Output transposed bf16 [h*64+d][t].
// ---------------------------------------------------------------------------
__global__ __launch_bounds__(256) void attn_kernel(const ushort* __restrict__ qkvT,
                                                   const float* __restrict__ pos_bias,
                                                   ushort* __restrict__ outT) {
    constexpr int OFF[NO] = {0, 1, 2, 3, 4, 6, 8, 12, 16, 24, 32, 48, 64, 96, 128,
                             192, 256, 384, 512, 768, 1024, 1536, 2048, 3072};
    // chunked XCD swizzle: 256 blocks -> 8 chunks of 32 (each XCD ~2 heads)
    const int bid = (blockIdx.x & 7) * 32 + (blockIdx.x >> 3);
    const int unit = bid * 4 + (threadIdx.x >> 6);
    const int lane = threadIdx.x & 63;
    const int h = unit >> 6;
    const int t = (unit & 63) * 64 + lane;

    const ushort* qd = qkvT + (size_t)(h * HDD) * NN;  // + d*NN
    const ushort* kd = qd + (size_t)DD * NN;
    const ushort* vd = qd + (size_t)(2 * DD) * NN;

    int kidx[NO];
#pragma unroll
    for (int j = 0; j < NO; ++j) kidx[j] = max(t - OFF[j], 0);

    float sc[NO];
#pragma unroll
    for (int j = 0; j < NO; ++j) sc[j] = 0.f;

#pragma unroll 4
    for (int d = 0; d < HDD; ++d) {
        const float qv = bf2f(qd[(size_t)d * NN + t]);
        const ushort* kr = kd + (size_t)d * NN;
#pragma unroll
        for (int j = 0; j < NO; ++j) sc[j] = fmaf(qv, bf2f(kr[kidx[j]]), sc[j]);
    }

    // score = valid ? dot*scale + pb : pb
#pragma unroll
    for (int j = 0; j < NO; ++j) {
        const float pb = pos_bias[j * HH + h];
        sc[j] = (t >= OFF[j]) ? fmaf(sc[j], 0.125f, pb) : pb;
    }

    float mx = sc[0];
#pragma unroll
    for (int j = 1; j < NO; ++j) mx = fmaxf(mx, sc[j]);
    float den = 0.f;
#pragma unroll
    for (int j = 0; j < NO; ++j) {
        sc[j] = __expf(sc[j] - mx);
        den += sc[j];
    }
    const float inv = 1.f / den;
#pragma unroll
    for (int j = 0; j < NO; ++j) sc[j] = (t >= OFF[j]) ? sc[j] * inv : 0.f;

#pragma unroll 4
    for (int d = 0; d < HDD; ++d) {
        const ushort* vr = vd + (size_t)d * NN;
        float o = 0.f;
#pragma unroll
        for (int j = 0; j < NO; ++j) o = fmaf(sc[j], bf2f(vr[kidx[j]]), o);
        outT[(size_t)(h * HDD + d) * NN + t] = f2bf(o);
    }
}

extern "C" void kernel_launch(void* const* d_in, const int* in_sizes, int n_in,
                              void* d_out, int out_size, void* d_ws, size_t ws_size,
                              hipStream_t stream) {
    const float* x = (const float*)d_in[0];
    const float* Wqkv = (const float*)d_in[1];
    const float* bqkv = (const float*)d_in[2];
    const float* Wout = (const float*)d_in[3];
    const float* bout = (const float*)d_in[4];
    const float* Wgate = (const float*)d_in[5];
    const float* bgate = (const float*)d_in[6];
    const float* pos_bias = (const float*)d_in[7];
    float* out = (float*)d_out;

    // workspace layout (58 MB peak)
    char* ws = (char*)d_ws;
    ushort* xb = (ushort*)ws;                            // 8 MB  [4096,1024] bf16
    ushort* WqkvT = (ushort*)(ws + ((size_t)8 << 20));   // 6 MB  [3072,1024] bf16
    ushort* WgateT = (ushort*)(ws + ((size_t)14 << 20)); // 2 MB
    ushort* WoutT = (ushort*)(ws + ((size_t)16 << 20));  // 2 MB
    ushort* qkvT = (ushort*)(ws + ((size_t)18 << 20));   // 24 MB [3072][4096] bf16
    ushort* outT = (ushort*)(ws + ((size_t)42 << 20));   // 8 MB  [1024][4096] bf16
    ushort* gated = (ushort*)(ws + ((size_t)50 << 20));  // 8 MB  [4096,1024] bf16

    // 0) converts / transposes
    f2b_kernel<<<(NN * DD / 4 + 255) / 256, 256, 0, stream>>>(x, xb, NN * DD / 4);
    transpose_f2b<<<dim3(QKV_N / 32, DD / 32), 256, 0, stream>>>(Wqkv, WqkvT, DD, QKV_N);
    transpose_f2b<<<dim3(DD / 32, DD / 32), 256, 0, stream>>>(Wgate, WgateT, DD, DD);
    transpose_f2b<<<dim3(DD / 32, DD / 32), 256, 0, stream>>>(Wout, WoutT, DD, DD);

    // 1) qkvT = (x @ Wqkv + bqkv)^T  bf16 [3072][4096]
    mfma_gemm<3><<<dim3(QKV_N / 128, NN / 128), 256, 0, stream>>>(
        xb, WqkvT, bqkv, nullptr, qkvT, NN, QKV_N, DD);
    // 2) attention -> outT bf16 [1024][4096]  (256 blocks x 4 indep waves)
    attn_kernel<<<256, 256, 0, stream>>>(qkvT, pos_bias, outT);
    // 3) gated = outT^T * sigmoid(x @ Wgate + bgate)  bf16 [4096][1024]
    mfma_gemm<2><<<dim3(DD / 128, NN / 128), 256, 0, stream>>>(
        xb, WgateT, bgate, outT, gated, NN, DD, DD);
    // 4) out = gated @ Wout + bout  fp32
    mfma_gemm<0><<<dim3(DD / 128, NN / 128), 256, 0, stream>>>(
        gated, WoutT, bout, nullptr, out, NN, DD, DD);
}

// Round 11
// 211.946 us; speedup vs baseline: 1.3731x; 1.2681x over previous
//
#include <hip/hip_runtime.h>
#include <hip/hip_bf16.h>

#define NN 4096
#define DD 1024
#define HH 16
#define HDD 64
#define NO 24
#define QKV_N (3 * DD)

typedef short bf16x8 __attribute__((ext_vector_type(8)));
typedef float f32x4 __attribute__((ext_vector_type(4)));
typedef unsigned short ushort;

// fp32 -> bf16 (RNE)
__device__ __forceinline__ ushort f2bf(float f) {
    unsigned u = __float_as_uint(f);
    return (ushort)((u + 0x7FFFu + ((u >> 16) & 1u)) >> 16);
}
__device__ __forceinline__ float bf2f(ushort u) {
    return __uint_as_float(((unsigned)u) << 16);
}

__device__ __forceinline__ void gload16(const void* g, void* l) {
    __builtin_amdgcn_global_load_lds((const __attribute__((address_space(1))) void*)g,
                                     (__attribute__((address_space(3))) void*)l, 16, 0, 0);
}

// dyadic offset formula: delta(0)=0, delta(1)=1, else (2+(j&1)) << ((j>>1)-1)
__device__ __forceinline__ int tap_delta(int j) {
    return j < 2 ? j : (2 + (j & 1)) << ((j >> 1) - 1);
}

// ---------------------------------------------------------------------------
// elementwise fp32 -> bf16
// ---------------------------------------------------------------------------
__global__ __launch_bounds__(256) void f2b_kernel(const float* __restrict__ in,
                                                  ushort* __restrict__ out, int n4) {
    int i = blockIdx.x * 256 + threadIdx.x;
    if (i < n4) {
        float4 v = ((const float4*)in)[i];
        ushort4 o;
        o.x = f2bf(v.x); o.y = f2bf(v.y); o.z = f2bf(v.z); o.w = f2bf(v.w);
        ((ushort4*)out)[i] = o;
    }
}

// ---------------------------------------------------------------------------
// transpose fp32 [R,C] -> bf16 [C,R]
// ---------------------------------------------------------------------------
__global__ __launch_bounds__(256) void transpose_f2b(const float* __restrict__ in,
                                                     ushort* __restrict__ out,
                                                     int R, int C) {
    __shared__ float tile[32][33];
    const int c0 = blockIdx.x * 32, r0 = blockIdx.y * 32;
    const int tx = threadIdx.x & 31, ty = threadIdx.x >> 5;
#pragma unroll
    for (int i = 0; i < 32; i += 8)
        tile[ty + i][tx] = in[(size_t)(r0 + ty + i) * C + c0 + tx];
    __syncthreads();
#pragma unroll
    for (int i = 0; i < 32; i += 8)
        out[(size_t)(c0 + ty + i) * R + r0 + tx] = f2bf(tile[tx][ty + i]);
}

// ---------------------------------------------------------------------------
// bf16 MFMA GEMM: C = A[M,K] @ BT[N,K]^T + bias
// 128x128 tile, BK=32, 4 waves x (4x4) 16x16x32 frags, global_load_lds dbuf,
// XOR-swizzled LDS (slot ^= (row>>1)&3) via pre-swizzled global source.
// OP==0: fp32 out[m*N+n] = acc + bias
// OP==1: bf16 out[m*N+n] = acc + bias
// OP==2: bf16 out = mult[m*N+n] * sigmoid(acc + bias)   (mult bf16 [M][N])
// ---------------------------------------------------------------------------
template <int OP>
__global__ __launch_bounds__(256) void mfma_gemm(const ushort* __restrict__ A,
                                                 const ushort* __restrict__ BT,
                                                 const float* __restrict__ bias,
                                                 const void* __restrict__ mult,
                                                 void* __restrict__ Cout,
                                                 int M, int N, int K) {
    __shared__ ushort sA[2][128 * 32];
    __shared__ ushort sB[2][128 * 32];

    const int tid = threadIdx.x;
    const int lane = tid & 63;
    const int w = tid >> 6;
    const int wr = w >> 1, wc = w & 1;
    const int m0 = blockIdx.y * 128, n0 = blockIdx.x * 128;

    const int row0 = tid >> 2, slot = tid & 3;
    const int row1 = row0 + 64;
    const int sw0 = slot ^ ((row0 >> 1) & 3);
    const int sw1 = slot ^ ((row1 >> 1) & 3);
    const int dst0 = (tid & ~63) * 8;
    const int dst1 = (256 + (tid & ~63)) * 8;

    const size_t aOff0 = (size_t)(m0 + row0) * K + sw0 * 8;
    const size_t aOff1 = (size_t)(m0 + row1) * K + sw1 * 8;
    const size_t bOff0 = (size_t)(n0 + row0) * K + sw0 * 8;
    const size_t bOff1 = (size_t)(n0 + row1) * K + sw1 * 8;

    const int ks = lane >> 4;
    int aRd[4], bRd[4];
#pragma unroll
    for (int m = 0; m < 4; ++m) {
        int r = wr * 64 + m * 16 + (lane & 15);
        aRd[m] = r * 64 + ((ks ^ ((r >> 1) & 3)) << 4);
    }
#pragma unroll
    for (int n = 0; n < 4; ++n) {
        int r = wc * 64 + n * 16 + (lane & 15);
        bRd[n] = r * 64 + ((ks ^ ((r >> 1) & 3)) << 4);
    }

    f32x4 acc[4][4];
#pragma unroll
    for (int m = 0; m < 4; ++m)
#pragma unroll
        for (int n = 0; n < 4; ++n) acc[m][n] = (f32x4){0.f, 0.f, 0.f, 0.f};

#define STAGE(buf, k0)                                              \
    do {                                                            \
        gload16(A + aOff0 + (k0), &sA[buf][dst0]);                  \
        gload16(A + aOff1 + (k0), &sA[buf][dst1]);                  \
        gload16(BT + bOff0 + (k0), &sB[buf][dst0]);                 \
        gload16(BT + bOff1 + (k0), &sB[buf][dst1]);                 \
    } while (0)

    const int NS = K >> 5;
    STAGE(0, 0);
    for (int s = 0; s < NS; ++s) {
        const int cur = s & 1;
        __syncthreads();
        if (s + 1 < NS) STAGE(cur ^ 1, (s + 1) * 32);
        const char* pa = (const char*)sA[cur];
        const char* pb = (const char*)sB[cur];
        bf16x8 af[4], bfr[4];
#pragma unroll
        for (int m = 0; m < 4; ++m) af[m] = *(const bf16x8*)(pa + aRd[m]);
#pragma unroll
        for (int n = 0; n < 4; ++n) bfr[n] = *(const bf16x8*)(pb + bRd[n]);
#pragma unroll
        for (int m = 0; m < 4; ++m)
#pragma unroll
            for (int n = 0; n < 4; ++n)
                acc[m][n] = __builtin_amdgcn_mfma_f32_16x16x32_bf16(af[m], bfr[n],
                                                                    acc[m][n], 0, 0, 0);
    }
#undef STAGE

    // C/D layout: col = lane&15, row = (lane>>4)*4 + j
    const int fr = lane & 15, fq = lane >> 4;
#pragma unroll
    for (int m = 0; m < 4; ++m) {
        const int rbase = m0 + wr * 64 + m * 16 + fq * 4;
#pragma unroll
        for (int n = 0; n < 4; ++n) {
            const int col = n0 + wc * 64 + n * 16 + fr;
            const float bv = bias[col];
#pragma unroll
            for (int j = 0; j < 4; ++j) {
                float v = acc[m][n][j] + bv;
                if (OP == 0) {
                    ((float*)Cout)[(size_t)(rbase + j) * N + col] = v;
                } else if (OP == 1) {
                    ((ushort*)Cout)[(size_t)(rbase + j) * N + col] = f2bf(v);
                } else {
                    const float mu =
                        bf2f(((const ushort*)mult)[(size_t)(rbase + j) * N + col]);
                    v = mu / (1.f + expf(-v));
                    ((ushort*)Cout)[(size_t)(rbase + j) * N + col] = f2bf(v);
                }
            }
        }
    }
}

// ---------------------------------------------------------------------------
// Attention v4: one WAVE per (t, h); lane = (g = tap-group 0..7, e = d-octet).
// qkv plain bf16 [t][3*1024]. One dwordx4 gather serves 8 taps' K-row
// head-slices (8 rows x 128 B, all bytes used) -> 11 vmem instrs per wave
// (vs ~50 in v3): q 1 + k 3 + v 3 + pos_bias 3 + store 1. Breaks the
// per-CU vmem-instruction-in-flight cap that pinned v1/v2/v3 at ~90-120 us.
// d-reduce: shfl_xor 1/2/4 within group; softmax + PV reduce over groups
// via shfl_xor 8/16/32. Invalid taps: clamped row + score=pb (in denom),
// p=0 (zero value) — matches reference zero-padded gather.
// ---------------------------------------------------------------------------
__global__ __launch_bounds__(256) void attn_kernel(const ushort* __restrict__ qkv,
                                                   const float* __restrict__ pos_bias,
                                                   ushort* __restrict__ outp) {
    // 16384 blocks -> bijective XCD chunk swizzle (2048 blocks = 2 heads/XCD)
    const int bid = (blockIdx.x & 7) * 2048 + (blockIdx.x >> 3);
    const int w = threadIdx.x >> 6;
    const int lane = threadIdx.x & 63;
    const int g = lane >> 3;  // tap sub-index within round
    const int e = lane & 7;   // d-octet
    const int h = bid >> 10;
    const int t = (bid & 1023) * 4 + w;

    const int d0 = h * HDD + e * 8;

    // Q slice (broadcast across groups)
    bf16x8 q8 = *(const bf16x8*)(qkv + (size_t)t * QKV_N + d0);
    float qf[8];
#pragma unroll
    for (int i = 0; i < 8; ++i) qf[i] = bf2f((ushort)q8[i]);

    // --- QK: 3 rounds of 8-tap gathers ---
    float sc[3];
    float pv_p[3];
    int rowz[3];
    bool valid[3];
#pragma unroll
    for (int r = 0; r < 3; ++r) {
        const int j = 8 * r + g;
        const int dlt = tap_delta(j);
        valid[r] = (t >= dlt);
        rowz[r] = valid[r] ? (t - dlt) : 0;
        bf16x8 k8 = *(const bf16x8*)(qkv + (size_t)rowz[r] * QKV_N + DD + d0);
        float dot = 0.f;
#pragma unroll
        for (int i = 0; i < 8; ++i) dot = fmaf(qf[i], bf2f((ushort)k8[i]), dot);
        dot += __shfl_xor(dot, 1);
        dot += __shfl_xor(dot, 2);
        dot += __shfl_xor(dot, 4);
        const float pb = pos_bias[j * HH + h];
        sc[r] = valid[r] ? fmaf(dot, 0.125f, pb) : pb;
    }

    // --- softmax over 24 taps (3 local x 8 groups) ---
    float mx = fmaxf(fmaxf(sc[0], sc[1]), sc[2]);
    mx = fmaxf(mx, __shfl_xor(mx, 8));
    mx = fmaxf(mx, __shfl_xor(mx, 16));
    mx = fmaxf(mx, __shfl_xor(mx, 32));
    float ex[3];
#pragma unroll
    for (int r = 0; r < 3; ++r) ex[r] = __expf(sc[r] - mx);
    float den = ex[0] + ex[1] + ex[2];
    den += __shfl_xor(den, 8);
    den += __shfl_xor(den, 16);
    den += __shfl_xor(den, 32);
    const float inv = 1.f / den;
#pragma unroll
    for (int r = 0; r < 3; ++r) pv_p[r] = valid[r] ? ex[r] * inv : 0.f;

    // --- PV: 3 rounds of 8-tap V gathers ---
    float o[8];
#pragma unroll
    for (int i = 0; i < 8; ++i) o[i] = 0.f;
#pragma unroll
    for (int r = 0; r < 3; ++r) {
        bf16x8 v8 = *(const bf16x8*)(qkv + (size_t)rowz[r] * QKV_N + 2 * DD + d0);
#pragma unroll
        for (int i = 0; i < 8; ++i) o[i] = fmaf(pv_p[r], bf2f((ushort)v8[i]), o[i]);
    }
    // reduce over the 8 tap-groups
#pragma unroll
    for (int i = 0; i < 8; ++i) {
        o[i] += __shfl_xor(o[i], 8);
        o[i] += __shfl_xor(o[i], 16);
        o[i] += __shfl_xor(o[i], 32);
    }

    if (g == 0) {
        bf16x8 o8;
#pragma unroll
        for (int i = 0; i < 8; ++i) o8[i] = (short)f2bf(o[i]);
        *(bf16x8*)(outp + (size_t)t * DD + d0) = o8;
    }
}

extern "C" void kernel_launch(void* const* d_in, const int* in_sizes, int n_in,
                              void* d_out, int out_size, void* d_ws, size_t ws_size,
                              hipStream_t stream) {
    const float* x = (const float*)d_in[0];
    const float* Wqkv = (const float*)d_in[1];
    const float* bqkv = (const float*)d_in[2];
    const float* Wout = (const float*)d_in[3];
    const float* bout = (const float*)d_in[4];
    const float* Wgate = (const float*)d_in[5];
    const float* bgate = (const float*)d_in[6];
    const float* pos_bias = (const float*)d_in[7];
    float* out = (float*)d_out;

    // workspace layout (58 MB peak)
    char* ws = (char*)d_ws;
    ushort* xb = (ushort*)ws;                            // 8 MB  [4096,1024] bf16
    ushort* WqkvT = (ushort*)(ws + ((size_t)8 << 20));   // 6 MB  [3072,1024] bf16
    ushort* WgateT = (ushort*)(ws + ((size_t)14 << 20)); // 2 MB
    ushort* WoutT = (ushort*)(ws + ((size_t)16 << 20));  // 2 MB
    ushort* qkv = (ushort*)(ws + ((size_t)18 << 20));    // 24 MB [4096][3072] bf16
    ushort* attno = (ushort*)(ws + ((size_t)42 << 20));  // 8 MB  [4096][1024] bf16
    ushort* gated = (ushort*)(ws + ((size_t)50 << 20));  // 8 MB  [4096][1024] bf16

    // 0) converts / transposes
    f2b_kernel<<<(NN * DD / 4 + 255) / 256, 256, 0, stream>>>(x, xb, NN * DD / 4);
    transpose_f2b<<<dim3(QKV_N / 32, DD / 32), 256, 0, stream>>>(Wqkv, WqkvT, DD, QKV_N);
    transpose_f2b<<<dim3(DD / 32, DD / 32), 256, 0, stream>>>(Wgate, WgateT, DD, DD);
    transpose_f2b<<<dim3(DD / 32, DD / 32), 256, 0, stream>>>(Wout, WoutT, DD, DD);

    // 1) qkv = x @ Wqkv + bqkv   bf16 [4096][3072] (plain)
    mfma_gemm<1><<<dim3(QKV_N / 128, NN / 128), 256, 0, stream>>>(
        xb, WqkvT, bqkv, nullptr, qkv, NN, QKV_N, DD);
    // 2) attention -> attno bf16 [4096][1024]  (16384 blocks x 4 waves)
    attn_kernel<<<16384, 256, 0, stream>>>(qkv, pos_bias, attno);
    // 3) gated = attno * sigmoid(x @ Wgate + bgate)  bf16 [4096][1024]
    mfma_gemm<2><<<dim3(DD / 128, NN / 128), 256, 0, stream>>>(
        xb, WgateT, bgate, attno, gated, NN, DD, DD);
    // 4) out = gated @ Wout + bout  fp32
    mfma_gemm<0><<<dim3(DD / 128, NN / 128), 256, 0, stream>>>(
        gated, WoutT, bout, nullptr, out, NN, DD, DD);
}

// Round 13
// 206.999 us; speedup vs baseline: 1.4059x; 1.0239x over previous
//
#include <hip/hip_runtime.h>
#include <hip/hip_bf16.h>

#define NN 4096
#define DD 1024
#define HH 16
#define HDD 64
#define NO 24
#define QG_N 4096  // qkvg row stride: [q 1024 | k 1024 | v 1024 | gate 1024]

typedef short bf16x8 __attribute__((ext_vector_type(8)));
typedef float f32x4 __attribute__((ext_vector_type(4)));
typedef unsigned short ushort;

// fp32 -> bf16 (RNE)
__device__ __forceinline__ ushort f2bf(float f) {
    unsigned u = __float_as_uint(f);
    return (ushort)((u + 0x7FFFu + ((u >> 16) & 1u)) >> 16);
}
__device__ __forceinline__ float bf2f(ushort u) {
    return __uint_as_float(((unsigned)u) << 16);
}

__device__ __forceinline__ void gload16(const void* g, void* l) {
    __builtin_amdgcn_global_load_lds((const __attribute__((address_space(1))) void*)g,
                                     (__attribute__((address_space(3))) void*)l, 16, 0, 0);
}

// dyadic offset formula: delta(0)=0, delta(1)=1, else (2+(j&1)) << ((j>>1)-1)
__device__ __forceinline__ int tap_delta(int j) {
    return j < 2 ? j : (2 + (j & 1)) << ((j >> 1) - 1);
}

// ---------------------------------------------------------------------------
// elementwise fp32 -> bf16
// ---------------------------------------------------------------------------
__global__ __launch_bounds__(256) void f2b_kernel(const float* __restrict__ in,
                                                  ushort* __restrict__ out, int n4) {
    int i = blockIdx.x * 256 + threadIdx.x;
    if (i < n4) {
        float4 v = ((const float4*)in)[i];
        ushort4 o;
        o.x = f2bf(v.x); o.y = f2bf(v.y); o.z = f2bf(v.z); o.w = f2bf(v.w);
        ((ushort4*)out)[i] = o;
    }
}

// ---------------------------------------------------------------------------
// transpose fp32 [R,C] -> bf16 [C,R]
// ---------------------------------------------------------------------------
__global__ __launch_bounds__(256) void transpose_f2b(const float* __restrict__ in,
                                                     ushort* __restrict__ out,
                                                     int R, int C) {
    __shared__ float tile[32][33];
    const int c0 = blockIdx.x * 32, r0 = blockIdx.y * 32;
    const int tx = threadIdx.x & 31, ty = threadIdx.x >> 5;
#pragma unroll
    for (int i = 0; i < 32; i += 8)
        tile[ty + i][tx] = in[(size_t)(r0 + ty + i) * C + c0 + tx];
    __syncthreads();
#pragma unroll
    for (int i = 0; i < 32; i += 8)
        out[(size_t)(c0 + ty + i) * R + r0 + tx] = f2bf(tile[tx][ty + i]);
}

// ---------------------------------------------------------------------------
// bf16 MFMA GEMM: C = A[M,K] @ BT[N,K]^T + bias, optional sigmoid band.
// 128x128 tile, BK=32, 4 waves x (4x4) 16x16x32 frags, global_load_lds dbuf,
// XOR-swizzled LDS (slot ^= (row>>1)&3) via pre-swizzled global source.
// bias: col < sigStart -> bias0[col], else bias1[col-sigStart] AND sigmoid.
// OP==0: fp32 out;  OP==1: bf16 out.
// ---------------------------------------------------------------------------
template <int OP>
__global__ __launch_bounds__(256) void mfma_gemm(const ushort* __restrict__ A,
                                                 const ushort* __restrict__ BT,
                                                 const float* __restrict__ bias0,
                                                 const float* __restrict__ bias1,
                                                 int sigStart,
                                                 void* __restrict__ Cout,
                                                 int M, int N, int K) {
    __shared__ ushort sA[2][128 * 32];
    __shared__ ushort sB[2][128 * 32];

    const int tid = threadIdx.x;
    const int lane = tid & 63;
    const int w = tid >> 6;
    const int wr = w >> 1, wc = w & 1;
    const int m0 = blockIdx.y * 128, n0 = blockIdx.x * 128;

    const int row0 = tid >> 2, slot = tid & 3;
    const int row1 = row0 + 64;
    const int sw0 = slot ^ ((row0 >> 1) & 3);
    const int sw1 = slot ^ ((row1 >> 1) & 3);
    const int dst0 = (tid & ~63) * 8;
    const int dst1 = (256 + (tid & ~63)) * 8;

    const size_t aOff0 = (size_t)(m0 + row0) * K + sw0 * 8;
    const size_t aOff1 = (size_t)(m0 + row1) * K + sw1 * 8;
    const size_t bOff0 = (size_t)(n0 + row0) * K + sw0 * 8;
    const size_t bOff1 = (size_t)(n0 + row1) * K + sw1 * 8;

    const int ks = lane >> 4;
    int aRd[4], bRd[4];
#pragma unroll
    for (int m = 0; m < 4; ++m) {
        int r = wr * 64 + m * 16 + (lane & 15);
        aRd[m] = r * 64 + ((ks ^ ((r >> 1) & 3)) << 4);
    }
#pragma unroll
    for (int n = 0; n < 4; ++n) {
        int r = wc * 64 + n * 16 + (lane & 15);
        bRd[n] = r * 64 + ((ks ^ ((r >> 1) & 3)) << 4);
    }

    f32x4 acc[4][4];
#pragma unroll
    for (int m = 0; m < 4; ++m)
#pragma unroll
        for (int n = 0; n < 4; ++n) acc[m][n] = (f32x4){0.f, 0.f, 0.f, 0.f};

#define STAGE(buf, k0)                                              \
    do {                                                            \
        gload16(A + aOff0 + (k0), &sA[buf][dst0]);                  \
        gload16(A + aOff1 + (k0), &sA[buf][dst1]);                  \
        gload16(BT + bOff0 + (k0), &sB[buf][dst0]);                 \
        gload16(BT + bOff1 + (k0), &sB[buf][dst1]);                 \
    } while (0)

    const int NS = K >> 5;
    STAGE(0, 0);
    for (int s = 0; s < NS; ++s) {
        const int cur = s & 1;
        __syncthreads();
        if (s + 1 < NS) STAGE(cur ^ 1, (s + 1) * 32);
        const char* pa = (const char*)sA[cur];
        const char* pb = (const char*)sB[cur];
        bf16x8 af[4], bfr[4];
#pragma unroll
        for (int m = 0; m < 4; ++m) af[m] = *(const bf16x8*)(pa + aRd[m]);
#pragma unroll
        for (int n = 0; n < 4; ++n) bfr[n] = *(const bf16x8*)(pb + bRd[n]);
#pragma unroll
        for (int m = 0; m < 4; ++m)
#pragma unroll
            for (int n = 0; n < 4; ++n)
                acc[m][n] = __builtin_amdgcn_mfma_f32_16x16x32_bf16(af[m], bfr[n],
                                                                    acc[m][n], 0, 0, 0);
    }
#undef STAGE

    // C/D layout: col = lane&15, row = (lane>>4)*4 + j
    const int fr = lane & 15, fq = lane >> 4;
#pragma unroll
    for (int m = 0; m < 4; ++m) {
        const int rbase = m0 + wr * 64 + m * 16 + fq * 4;
#pragma unroll
        for (int n = 0; n < 4; ++n) {
            const int col = n0 + wc * 64 + n * 16 + fr;
            const bool sig = (col >= sigStart);
            const float bv = sig ? bias1[col - sigStart] : bias0[col];
#pragma unroll
            for (int j = 0; j < 4; ++j) {
                float v = acc[m][n][j] + bv;
                if (sig) v = 1.f / (1.f + expf(-v));
                if (OP == 0) {
                    ((float*)Cout)[(size_t)(rbase + j) * N + col] = v;
                } else {
                    ((ushort*)Cout)[(size_t)(rbase + j) * N + col] = f2bf(v);
                }
            }
        }
    }
}

// ---------------------------------------------------------------------------
// Attention v5 = v4 + fused gate multiply. One WAVE per (t, h);
// lane = (g = tap-group 0..7, e = d-octet). qkvg bf16 [t][4096] =
// [q|k|v|gate]. One dwordx4 gather serves 8 taps' K-row head-slices ->
// 12 vmem instrs per wave. d-reduce: shfl_xor 1/2/4; softmax + PV reduce
// over groups via shfl_xor 8/16/32. Invalid taps: clamped row +
// score=pb (in denom), p=0. Store: out = attn * gate (gate precomputed
// sigmoid in GEMM epilogue, same row -> L2 hit).
// ---------------------------------------------------------------------------
__global__ __launch_bounds__(256) void attn_kernel(const ushort* __restrict__ qkvg,
                                                   const float* __restrict__ pos_bias,
                                                   ushort* __restrict__ outp) {
    // 16384 blocks -> bijective XCD chunk swizzle (2048 blocks = 2 heads/XCD)
    const int bid = (blockIdx.x & 7) * 2048 + (blockIdx.x >> 3);
    const int w = threadIdx.x >> 6;
    const int lane = threadIdx.x & 63;
    const int g = lane >> 3;  // tap sub-index within round
    const int e = lane & 7;   // d-octet
    const int h = bid >> 10;
    const int t = (bid & 1023) * 4 + w;

    const int d0 = h * HDD + e * 8;

    // Q slice (broadcast across groups)
    bf16x8 q8 = *(const bf16x8*)(qkvg + (size_t)t * QG_N + d0);
    float qf[8];
#pragma unroll
    for (int i = 0; i < 8; ++i) qf[i] = bf2f((ushort)q8[i]);

    // --- QK: 3 rounds of 8-tap gathers ---
    float sc[3];
    float pv_p[3];
    int rowz[3];
    bool valid[3];
#pragma unroll
    for (int r = 0; r < 3; ++r) {
        const int j = 8 * r + g;
        const int dlt = tap_delta(j);
        valid[r] = (t >= dlt);
        rowz[r] = valid[r] ? (t - dlt) : 0;
        bf16x8 k8 = *(const bf16x8*)(qkvg + (size_t)rowz[r] * QG_N + DD + d0);
        float dot = 0.f;
#pragma unroll
        for (int i = 0; i < 8; ++i) dot = fmaf(qf[i], bf2f((ushort)k8[i]), dot);
        dot += __shfl_xor(dot, 1);
        dot += __shfl_xor(dot, 2);
        dot += __shfl_xor(dot, 4);
        const float pb = pos_bias[j * HH + h];
        sc[r] = valid[r] ? fmaf(dot, 0.125f, pb) : pb;
    }

    // --- softmax over 24 taps (3 local x 8 groups) ---
    float mx = fmaxf(fmaxf(sc[0], sc[1]), sc[2]);
    mx = fmaxf(mx, __shfl_xor(mx, 8));
    mx = fmaxf(mx, __shfl_xor(mx, 16));
    mx = fmaxf(mx, __shfl_xor(mx, 32));
    float ex[3];
#pragma unroll
    for (int r = 0; r < 3; ++r) ex[r] = __expf(sc[r] - mx);
    float den = ex[0] + ex[1] + ex[2];
    den += __shfl_xor(den, 8);
    den += __shfl_xor(den, 16);
    den += __shfl_xor(den, 32);
    const float inv = 1.f / den;
#pragma unroll
    for (int r = 0; r < 3; ++r) pv_p[r] = valid[r] ? ex[r] * inv : 0.f;

    // --- PV: 3 rounds of 8-tap V gathers ---
    float o[8];
#pragma unroll
    for (int i = 0; i < 8; ++i) o[i] = 0.f;
#pragma unroll
    for (int r = 0; r < 3; ++r) {
        bf16x8 v8 = *(const bf16x8*)(qkvg + (size_t)rowz[r] * QG_N + 2 * DD + d0);
#pragma unroll
        for (int i = 0; i < 8; ++i) o[i] = fmaf(pv_p[r], bf2f((ushort)v8[i]), o[i]);
    }
    // reduce over the 8 tap-groups
#pragma unroll
    for (int i = 0; i < 8; ++i) {
        o[i] += __shfl_xor(o[i], 8);
        o[i] += __shfl_xor(o[i], 16);
        o[i] += __shfl_xor(o[i], 32);
    }

    if (g == 0) {
        // fused gate multiply: gate = sigmoid(x@Wgate+bgate), precomputed bf16
        bf16x8 g8 = *(const bf16x8*)(qkvg + (size_t)t * QG_N + 3 * DD + d0);
        bf16x8 o8;
#pragma unroll
        for (int i = 0; i < 8; ++i)
            o8[i] = (short)f2bf(o[i] * bf2f((ushort)g8[i]));
        *(bf16x8*)(outp + (size_t)t * DD + d0) = o8;
    }
}

extern "C" void kernel_launch(void* const* d_in, const int* in_sizes, int n_in,
                              void* d_out, int out_size, void* d_ws, size_t ws_size,
                              hipStream_t stream) {
    const float* x = (const float*)d_in[0];
    const float* Wqkv = (const float*)d_in[1];
    const float* bqkv = (const float*)d_in[2];
    const float* Wout = (const float*)d_in[3];
    const float* bout = (const float*)d_in[4];
    const float* Wgate = (const float*)d_in[5];
    const float* bgate = (const float*)d_in[6];
    const float* pos_bias = (const float*)d_in[7];
    float* out = (float*)d_out;

    // workspace layout (58 MB peak)
    char* ws = (char*)d_ws;
    ushort* xb = (ushort*)ws;                            // 8 MB  [4096,1024] bf16
    ushort* WcatT = (ushort*)(ws + ((size_t)8 << 20));   // 8 MB  [4096,1024] bf16
    ushort* WoutT = (ushort*)(ws + ((size_t)16 << 20));  // 2 MB  [1024,1024] bf16
    ushort* qkvg = (ushort*)(ws + ((size_t)18 << 20));   // 32 MB [4096][4096] bf16
    ushort* gated = (ushort*)(ws + ((size_t)50 << 20));  // 8 MB  [4096][1024] bf16

    // 0) converts / transposes (WcatT rows: 0-3071 = Wqkv^T, 3072-4095 = Wgate^T)
    f2b_kernel<<<(NN * DD / 4 + 255) / 256, 256, 0, stream>>>(x, xb, NN * DD / 4);
    transpose_f2b<<<dim3(3 * DD / 32, DD / 32), 256, 0, stream>>>(Wqkv, WcatT, DD, 3 * DD);
    transpose_f2b<<<dim3(DD / 32, DD / 32), 256, 0, stream>>>(
        Wgate, WcatT + (size_t)3 * DD * DD, DD, DD);
    transpose_f2b<<<dim3(DD / 32, DD / 32), 256, 0, stream>>>(Wout, WoutT, DD, DD);

    // 1) qkvg = [x@Wqkv + bqkv | sigmoid(x@Wgate + bgate)]  bf16 [4096][4096]
    mfma_gemm<1><<<dim3(QG_N / 128, NN / 128), 256, 0, stream>>>(
        xb, WcatT, bqkv, bgate, 3 * DD, qkvg, NN, QG_N, DD);
    // 2) attention (+gate multiply) -> gated bf16 [4096][1024]
    attn_kernel<<<16384, 256, 0, stream>>>(qkvg, pos_bias, gated);
    // 3) out = gated @ Wout + bout  fp32
    mfma_gemm<0><<<dim3(DD / 128, NN / 128), 256, 0, stream>>>(
        gated, WoutT, bout, bout, 1 << 30, out, NN, DD, DD);
}

// Round 15
// 195.449 us; speedup vs baseline: 1.4890x; 1.0591x over previous
//
#include <hip/hip_runtime.h>
#include <hip/hip_bf16.h>

#define NN 4096
#define DD 1024
#define HH 16
#define HDD 64
#define NO 24
#define QG_N 4096  // qkvg row stride: [q 1024 | k 1024 | v 1024 | gate 1024]

typedef short bf16x8 __attribute__((ext_vector_type(8)));
typedef float f32x4 __attribute__((ext_vector_type(4)));
typedef unsigned short ushort;

// fp32 -> bf16 (RNE)
__device__ __forceinline__ ushort f2bf(float f) {
    unsigned u = __float_as_uint(f);
    return (ushort)((u + 0x7FFFu + ((u >> 16) & 1u)) >> 16);
}
__device__ __forceinline__ float bf2f(ushort u) {
    return __uint_as_float(((unsigned)u) << 16);
}

__device__ __forceinline__ void gload16(const void* g, void* l) {
    __builtin_amdgcn_global_load_lds((const __attribute__((address_space(1))) void*)g,
                                     (__attribute__((address_space(3))) void*)l, 16, 0, 0);
}

// raw barrier (no vmcnt drain) with compiler-level memory fence
#define BAR()                                  \
    do {                                       \
        asm volatile("" ::: "memory");         \
        __builtin_amdgcn_s_barrier();          \
        asm volatile("" ::: "memory");         \
    } while (0)

// dyadic offset formula: delta(0)=0, delta(1)=1, else (2+(j&1)) << ((j>>1)-1)
__device__ __forceinline__ int tap_delta(int j) {
    return j < 2 ? j : (2 + (j & 1)) << ((j >> 1) - 1);
}

// ---------------------------------------------------------------------------
// elementwise fp32 -> bf16
// ---------------------------------------------------------------------------
__global__ __launch_bounds__(256) void f2b_kernel(const float* __restrict__ in,
                                                  ushort* __restrict__ out, int n4) {
    int i = blockIdx.x * 256 + threadIdx.x;
    if (i < n4) {
        float4 v = ((const float4*)in)[i];
        ushort4 o;
        o.x = f2bf(v.x); o.y = f2bf(v.y); o.z = f2bf(v.z); o.w = f2bf(v.w);
        ((ushort4*)out)[i] = o;
    }
}

// ---------------------------------------------------------------------------
// transpose fp32 [R,C] -> bf16 [C,R]
// ---------------------------------------------------------------------------
__global__ __launch_bounds__(256) void transpose_f2b(const float* __restrict__ in,
                                                     ushort* __restrict__ out,
                                                     int R, int C) {
    __shared__ float tile[32][33];
    const int c0 = blockIdx.x * 32, r0 = blockIdx.y * 32;
    const int tx = threadIdx.x & 31, ty = threadIdx.x >> 5;
#pragma unroll
    for (int i = 0; i < 32; i += 8)
        tile[ty + i][tx] = in[(size_t)(r0 + ty + i) * C + c0 + tx];
    __syncthreads();
#pragma unroll
    for (int i = 0; i < 32; i += 8)
        out[(size_t)(c0 + ty + i) * R + r0 + tx] = f2bf(tile[tx][ty + i]);
}

// ---------------------------------------------------------------------------
// 256x256-tile 8-wave 4-phase counted-vmcnt bf16 GEMM (m201-template port).
// C[M,N] = A[M,K] @ BT[N,K]^T + bias, sigmoid band for col >= sigStart.
// BK=64, dbuf dynamic LDS 128 KB, raw s_barrier + counted vmcnt(4)/vmcnt(2)
// (never 0 in main loop). LDS slot-XOR swizzle (slot^=row&7) via
// pre-swizzled global source, swizzled ds_read (involution, rule #21).
// Per tile: issue order A01,B01,A23,B23 (2 gloads/phase); phases compute
// A0B0, A0B1, A1B1, A1B0 (16 MFMA each). Wave (wr,wc) in 2x4; interleaved
// frag maps: A rows mf*32+wr*16, B rows nf*64+wc*16 => each half-tile is
// whole load-chunks for ALL waves, so counted waits cover cross-wave use:
// each wave waits its own loads BEFORE the barrier; barrier then orders
// everyone's landed writes before any consuming ds_read.
// ---------------------------------------------------------------------------
__global__ __launch_bounds__(512) void mfma_gemm256(const ushort* __restrict__ A,
                                                    const ushort* __restrict__ BT,
                                                    const float* __restrict__ bias0,
                                                    const float* __restrict__ bias1,
                                                    int sigStart,
                                                    ushort* __restrict__ Cout,
                                                    int M, int N, int K) {
    extern __shared__ char lds[];  // [2][A 32KB | B 32KB] = 128 KB

    const int tid = threadIdx.x;
    const int lane = tid & 63;
    const int wid = tid >> 6;
    const int wr = wid >> 2;  // 0..1
    const int wc = wid & 3;   // 0..3

    // bijective XCD swizzle over 256 blocks (8 chunks of 32 = 2 m-rows/XCD)
    const int id = blockIdx.y * gridDim.x + blockIdx.x;
    const int swz = (id & 7) * 32 + (id >> 3);
    const int m0 = (swz >> 4) * 256, n0 = (swz & 15) * 256;

    // ---- staging (linear LDS dest; swizzled global source) ----
    // chunk c = i*512 + tid; row = i*64 + (tid>>3); slot = tid&7;
    // physical slot holds logical slot^(row&7) -> source col-slot = sw
    const int sw = (tid & 7) ^ ((tid >> 3) & 7);
    const int srow = tid >> 3;  // 0..63
    const size_t aBase = (size_t)(m0 + srow) * K + sw * 8;
    const size_t bBase = (size_t)(n0 + srow) * K + sw * 8;
    const int ldst = (tid & ~63) * 16;  // wave-uniform LDS byte offset

#define ISSUE_A(buf, i, k0) \
    gload16(A + aBase + (size_t)(i) * 64 * K + (k0), lds + (buf) * 65536 + (i) * 8192 + ldst)
#define ISSUE_B(buf, i, k0) \
    gload16(BT + bBase + (size_t)(i) * 64 * K + (k0), lds + (buf) * 65536 + 32768 + (i) * 8192 + ldst)

    // ---- ds_read fragment addressing ----
    // frag row bases are multiples of 16 => row&7 == lr&7
    const int lr = lane & 15;
    const int l47 = lane >> 4;  // 0..3
    const int r7 = lr & 7;

#define A_OFF(mf, ks) \
    (((mf) * 32 + wr * 16 + lr) * 128 + ((((ks) * 4 + l47) ^ r7) << 4))
#define B_OFF(nf, ks) \
    (32768 + ((nf) * 64 + wc * 16 + lr) * 128 + ((((ks) * 4 + l47) ^ r7) << 4))

    f32x4 acc[8][4];
#pragma unroll
    for (int m = 0; m < 8; ++m)
#pragma unroll
        for (int n = 0; n < 4; ++n) acc[m][n] = (f32x4){0.f, 0.f, 0.f, 0.f};

    bf16x8 ar[4][2], br[2][2];

#define LOAD_A_HALF(buf, h)                                                     \
    do {                                                                        \
        const char* p = lds + (buf) * 65536;                                    \
        _Pragma("unroll") for (int m2 = 0; m2 < 4; ++m2)                        \
            _Pragma("unroll") for (int ks = 0; ks < 2; ++ks)                    \
                ar[m2][ks] = *(const bf16x8*)(p + A_OFF((h) * 4 + m2, ks));     \
    } while (0)
#define LOAD_B_HALF(buf, h)                                                     \
    do {                                                                        \
        const char* p = lds + (buf) * 65536;                                    \
        _Pragma("unroll") for (int n2 = 0; n2 < 2; ++n2)                        \
            _Pragma("unroll") for (int ks = 0; ks < 2; ++ks)                    \
                br[n2][ks] = *(const bf16x8*)(p + B_OFF((h) * 2 + n2, ks));     \
    } while (0)
#define MFMA_QUAD(ah, bh)                                                       \
    do {                                                                        \
        __builtin_amdgcn_s_setprio(1);                                          \
        _Pragma("unroll") for (int m2 = 0; m2 < 4; ++m2)                        \
            _Pragma("unroll") for (int n2 = 0; n2 < 2; ++n2)                    \
                _Pragma("unroll") for (int ks = 0; ks < 2; ++ks)                \
                    acc[(ah) * 4 + m2][(bh) * 2 + n2] =                         \
                        __builtin_amdgcn_mfma_f32_16x16x32_bf16(                \
                            ar[m2][ks], br[n2][ks],                             \
                            acc[(ah) * 4 + m2][(bh) * 2 + n2], 0, 0, 0);        \
        __builtin_amdgcn_s_setprio(0);                                          \
    } while (0)

    // ---- prologue: stage tile 0 (issue order = steady-state order) ----
    ISSUE_A(0, 0, 0); ISSUE_A(0, 1, 0);
    ISSUE_B(0, 0, 0); ISSUE_B(0, 1, 0);
    ISSUE_A(0, 2, 0); ISSUE_A(0, 3, 0);
    ISSUE_B(0, 2, 0); ISSUE_B(0, 3, 0);

    const int NT = K >> 6;  // 16
    for (int t = 0; t < NT; ++t) {
        const int buf = t & 1;
        const int nxt = buf ^ 1;
        const int nk = (t + 1) * 64;
        const bool pf = (t + 1 < NT);  // wave-uniform

        // P0: needs A-half0 + B-half0 = oldest 4 outstanding
        asm volatile("s_waitcnt vmcnt(4)" ::: "memory");
        BAR();
        LOAD_A_HALF(buf, 0);
        LOAD_B_HALF(buf, 0);
        if (pf) { ISSUE_A(nxt, 0, nk); ISSUE_A(nxt, 1, nk); }
        BAR();
        MFMA_QUAD(0, 0);

        // P1: needs B-half1 (B23 of this tile)
        if (pf) {
            asm volatile("s_waitcnt vmcnt(2)" ::: "memory");
        } else {
            asm volatile("s_waitcnt vmcnt(0)" ::: "memory");
        }
        BAR();
        LOAD_B_HALF(buf, 1);
        if (pf) { ISSUE_B(nxt, 0, nk); ISSUE_B(nxt, 1, nk); }
        BAR();
        MFMA_QUAD(0, 1);

        // P2: needs A-half1 (already covered by P1's wait)
        BAR();
        LOAD_A_HALF(buf, 1);
        if (pf) { ISSUE_A(nxt, 2, nk); ISSUE_A(nxt, 3, nk); }
        BAR();
        MFMA_QUAD(1, 1);

        // P3: re-reads B-half0 (current buf, long landed)
        BAR();
        LOAD_B_HALF(buf, 0);
        if (pf) { ISSUE_B(nxt, 2, nk); ISSUE_B(nxt, 3, nk); }
        BAR();
        MFMA_QUAD(1, 0);
    }

    // ---- epilogue ----
    const int fr = lane & 15, fq = lane >> 4;
#pragma unroll
    for (int mf = 0; mf < 8; ++mf) {
        const int row = m0 + mf * 32 + wr * 16 + fq * 4;
#pragma unroll
        for (int nf = 0; nf < 4; ++nf) {
            const int col = n0 + nf * 64 + wc * 16 + fr;
            const bool sig = (col >= sigStart);
            const float bv = sig ? bias1[col - sigStart] : bias0[col];
#pragma unroll
            for (int j = 0; j < 4; ++j) {
                float v = acc[mf][nf][j] + bv;
                if (sig) v = 1.f / (1.f + expf(-v));
                Cout[(size_t)(row + j) * N + col] = f2bf(v);
            }
        }
    }
#undef ISSUE_A
#undef ISSUE_B
#undef A_OFF
#undef B_OFF
#undef LOAD_A_HALF
#undef LOAD_B_HALF
#undef MFMA_QUAD
}

// ---------------------------------------------------------------------------
// 128x128 bf16 MFMA GEMM (proven m97-style) for the out-projection.
// OP==0: fp32 out = acc + bias0.
// ---------------------------------------------------------------------------
template <int OP>
__global__ __launch_bounds__(256) void mfma_gemm(const ushort* __restrict__ A,
                                                 const ushort* __restrict__ BT,
                                                 const float* __restrict__ bias0,
                                                 void* __restrict__ Cout,
                                                 int M, int N, int K) {
    __shared__ ushort sA[2][128 * 32];
    __shared__ ushort sB[2][128 * 32];

    const int tid = threadIdx.x;
    const int lane = tid & 63;
    const int w = tid >> 6;
    const int wr = w >> 1, wc = w & 1;
    const int m0 = blockIdx.y * 128, n0 = blockIdx.x * 128;

    const int row0 = tid >> 2, slot = tid & 3;
    const int row1 = row0 + 64;
    const int sw0 = slot ^ ((row0 >> 1) & 3);
    const int sw1 = slot ^ ((row1 >> 1) & 3);
    const int dst0 = (tid & ~63) * 8;
    const int dst1 = (256 + (tid & ~63)) * 8;

    const size_t aOff0 = (size_t)(m0 + row0) * K + sw0 * 8;
    const size_t aOff1 = (size_t)(m0 + row1) * K + sw1 * 8;
    const size_t bOff0 = (size_t)(n0 + row0) * K + sw0 * 8;
    const size_t bOff1 = (size_t)(n0 + row1) * K + sw1 * 8;

    const int ks = lane >> 4;
    int aRd[4], bRd[4];
#pragma unroll
    for (int m = 0; m < 4; ++m) {
        int r = wr * 64 + m * 16 + (lane & 15);
        aRd[m] = r * 64 + ((ks ^ ((r >> 1) & 3)) << 4);
    }
#pragma unroll
    for (int n = 0; n < 4; ++n) {
        int r = wc * 64 + n * 16 + (lane & 15);
        bRd[n] = r * 64 + ((ks ^ ((r >> 1) & 3)) << 4);
    }

    f32x4 acc[4][4];
#pragma unroll
    for (int m = 0; m < 4; ++m)
#pragma unroll
        for (int n = 0; n < 4; ++n) acc[m][n] = (f32x4){0.f, 0.f, 0.f, 0.f};

#define STAGE(buf, k0)                                              \
    do {                                                            \
        gload16(A + aOff0 + (k0), &sA[buf][dst0]);                  \
        gload16(A + aOff1 + (k0), &sA[buf][dst1]);                  \
        gload16(BT + bOff0 + (k0), &sB[buf][dst0]);                 \
        gload16(BT + bOff1 + (k0), &sB[buf][dst1]);                 \
    } while (0)

    const int NS = K >> 5;
    STAGE(0, 0);
    for (int s = 0; s < NS; ++s) {
        const int cur = s & 1;
        __syncthreads();
        if (s + 1 < NS) STAGE(cur ^ 1, (s + 1) * 32);
        const char* pa = (const char*)sA[cur];
        const char* pb = (const char*)sB[cur];
        bf16x8 af[4], bfr[4];
#pragma unroll
        for (int m = 0; m < 4; ++m) af[m] = *(const bf16x8*)(pa + aRd[m]);
#pragma unroll
        for (int n = 0; n < 4; ++n) bfr[n] = *(const bf16x8*)(pb + bRd[n]);
#pragma unroll
        for (int m = 0; m < 4; ++m)
#pragma unroll
            for (int n = 0; n < 4; ++n)
                acc[m][n] = __builtin_amdgcn_mfma_f32_16x16x32_bf16(af[m], bfr[n],
                                                                    acc[m][n], 0, 0, 0);
    }
#undef STAGE

    const int fr = lane & 15, fq = lane >> 4;
#pragma unroll
    for (int m = 0; m < 4; ++m) {
        const int rbase = m0 + wr * 64 + m * 16 + fq * 4;
#pragma unroll
        for (int n = 0; n < 4; ++n) {
            const int col = n0 + wc * 64 + n * 16 + fr;
            const float bv = bias0[col];
#pragma unroll
            for (int j = 0; j < 4; ++j) {
                ((float*)Cout)[(size_t)(rbase + j) * N + col] = acc[m][n][j] + bv;
            }
        }
    }
}

// ---------------------------------------------------------------------------
// Attention v5 (proven): one WAVE per (t, h); lane = (tap-group, d-octet).
// qkvg bf16 [t][4096] = [q|k|v|gate]; fused gate multiply at store.
// ---------------------------------------------------------------------------
__global__ __launch_bounds__(256) void attn_kernel(const ushort* __restrict__ qkvg,
                                                   const float* __restrict__ pos_bias,
                                                   ushort* __restrict__ outp) {
    const int bid = (blockIdx.x & 7) * 2048 + (blockIdx.x >> 3);
    const int w = threadIdx.x >> 6;
    const int lane = threadIdx.x & 63;
    const int g = lane >> 3;
    const int e = lane & 7;
    const int h = bid >> 10;
    const int t = (bid & 1023) * 4 + w;

    const int d0 = h * HDD + e * 8;

    bf16x8 q8 = *(const bf16x8*)(qkvg + (size_t)t * QG_N + d0);
    float qf[8];
#pragma unroll
    for (int i = 0; i < 8; ++i) qf[i] = bf2f((ushort)q8[i]);

    float sc[3];
    float pv_p[3];
    int rowz[3];
    bool valid[3];
#pragma unroll
    for (int r = 0; r < 3; ++r) {
        const int j = 8 * r + g;
        const int dlt = tap_delta(j);
        valid[r] = (t >= dlt);
        rowz[r] = valid[r] ? (t - dlt) : 0;
        bf16x8 k8 = *(const bf16x8*)(qkvg + (size_t)rowz[r] * QG_N + DD + d0);
        float dot = 0.f;
#pragma unroll
        for (int i = 0; i < 8; ++i) dot = fmaf(qf[i], bf2f((ushort)k8[i]), dot);
        dot += __shfl_xor(dot, 1);
        dot += __shfl_xor(dot, 2);
        dot += __shfl_xor(dot, 4);
        const float pb = pos_bias[j * HH + h];
        sc[r] = valid[r] ? fmaf(dot, 0.125f, pb) : pb;
    }

    float mx = fmaxf(fmaxf(sc[0], sc[1]), sc[2]);
    mx = fmaxf(mx, __shfl_xor(mx, 8));
    mx = fmaxf(mx, __shfl_xor(mx, 16));
    mx = fmaxf(mx, __shfl_xor(mx, 32));
    float ex[3];
#pragma unroll
    for (int r = 0; r < 3; ++r) ex[r] = __expf(sc[r] - mx);
    float den = ex[0] + ex[1] + ex[2];
    den += __shfl_xor(den, 8);
    den += __shfl_xor(den, 16);
    den += __shfl_xor(den, 32);
    const float inv = 1.f / den;
#pragma unroll
    for (int r = 0; r < 3; ++r) pv_p[r] = valid[r] ? ex[r] * inv : 0.f;

    float o[8];
#pragma unroll
    for (int i = 0; i < 8; ++i) o[i] = 0.f;
#pragma unroll
    for (int r = 0; r < 3; ++r) {
        bf16x8 v8 = *(const bf16x8*)(qkvg + (size_t)rowz[r] * QG_N + 2 * DD + d0);
#pragma unroll
        for (int i = 0; i < 8; ++i) o[i] = fmaf(pv_p[r], bf2f((ushort)v8[i]), o[i]);
    }
#pragma unroll
    for (int i = 0; i < 8; ++i) {
        o[i] += __shfl_xor(o[i], 8);
        o[i] += __shfl_xor(o[i], 16);
        o[i] += __shfl_xor(o[i], 32);
    }

    if (g == 0) {
        bf16x8 g8 = *(const bf16x8*)(qkvg + (size_t)t * QG_N + 3 * DD + d0);
        bf16x8 o8;
#pragma unroll
        for (int i = 0; i < 8; ++i)
            o8[i] = (short)f2bf(o[i] * bf2f((ushort)g8[i]));
        *(bf16x8*)(outp + (size_t)t * DD + d0) = o8;
    }
}

extern "C" void kernel_launch(void* const* d_in, const int* in_sizes, int n_in,
                              void* d_out, int out_size, void* d_ws, size_t ws_size,
                              hipStream_t stream) {
    const float* x = (const float*)d_in[0];
    const float* Wqkv = (const float*)d_in[1];
    const float* bqkv = (const float*)d_in[2];
    const float* Wout = (const float*)d_in[3];
    const float* bout = (const float*)d_in[4];
    const float* Wgate = (const float*)d_in[5];
    const float* bgate = (const float*)d_in[6];
    const float* pos_bias = (const float*)d_in[7];
    float* out = (float*)d_out;

    // workspace layout (58 MB peak)
    char* ws = (char*)d_ws;
    ushort* xb = (ushort*)ws;                            // 8 MB  [4096,1024] bf16
    ushort* WcatT = (ushort*)(ws + ((size_t)8 << 20));   // 8 MB  [4096,1024] bf16
    ushort* WoutT = (ushort*)(ws + ((size_t)16 << 20));  // 2 MB  [1024,1024] bf16
    ushort* qkvg = (ushort*)(ws + ((size_t)18 << 20));   // 32 MB [4096][4096] bf16
    ushort* gated = (ushort*)(ws + ((size_t)50 << 20));  // 8 MB  [4096][1024] bf16

    // 0) converts / transposes (WcatT rows: 0-3071 = Wqkv^T, 3072-4095 = Wgate^T)
    f2b_kernel<<<(NN * DD / 4 + 255) / 256, 256, 0, stream>>>(x, xb, NN * DD / 4);
    transpose_f2b<<<dim3(3 * DD / 32, DD / 32), 256, 0, stream>>>(Wqkv, WcatT, DD, 3 * DD);
    transpose_f2b<<<dim3(DD / 32, DD / 32), 256, 0, stream>>>(
        Wgate, WcatT + (size_t)3 * DD * DD, DD, DD);
    transpose_f2b<<<dim3(DD / 32, DD / 32), 256, 0, stream>>>(Wout, WoutT, DD, DD);

    // 1) qkvg = [x@Wqkv + bqkv | sigmoid(x@Wgate + bgate)]  bf16 [4096][4096]
    hipFuncSetAttribute(reinterpret_cast<const void*>(mfma_gemm256),
                        hipFuncAttributeMaxDynamicSharedMemorySize, 131072);
    mfma_gemm256<<<dim3(16, 16), 512, 131072, stream>>>(
        xb, WcatT, bqkv, bgate, 3 * DD, qkvg, NN, QG_N, DD);
    // 2) attention (+gate multiply) -> gated bf16 [4096][1024]
    attn_kernel<<<16384, 256, 0, stream>>>(qkvg, pos_bias, gated);
    // 3) out = gated @ Wout + bout  fp32
    mfma_gemm<0><<<dim3(DD / 128, NN / 128), 256, 0, stream>>>(
        gated, WoutT, bout, out, NN, DD, DD);
}